// Round 4
// baseline (66.809 us; speedup 1.0000x reference)
//
#include <hip/hip_runtime.h>

#define Nn 512
#define Dd 128
#define Kk 2048
#define Cc 100
#define KC 4            // k-chunks per class
#define CHUNK 512       // cols per chunk = 128 colgroups * 4
#define G 8             // samples per pass
constexpr float INV_T = 1.0f / 0.07f;

// ws layout (floats): stats_m[n*KC+kc] at [0,2048), stats_s at [2048,4096)

__global__ __launch_bounds__(256) void chunk_kernel(
    const float* __restrict__ q,
    const float* __restrict__ queue, const int* __restrict__ labels,
    float* __restrict__ ws)
{
    const int c    = blockIdx.y;
    const int kc   = blockIdx.x;
    const int t    = threadIdx.x;
    const int gcol = t & 127;   // colgroup: 4 consecutive cols (float4)
    const int dq   = t >> 7;    // d-half: 64 d's each
    const int lane = t & 63;
    const int wid  = t >> 6;    // 0..3 (0,1 are the dq==0 waves)

    __shared__ int   s_list[Nn];
    __shared__ int   s_cnt;
    __shared__ float sq[Dd][G];          // staged q rows [d][s], 4 KB
    __shared__ float part[4][G][132];    // dq==1 partials, padded rows, 16.9 KB
    __shared__ float wmax[2][G];
    __shared__ float wsum[2][G];

    // wave-0 ballot scan: deterministic ordered list of samples with label c
    if (t < 64) {
        int cnt = 0;
        for (int base = 0; base < Nn; base += 64) {
            int lab = labels[base + t];
            unsigned long long m = __ballot(lab == c);
            if (lab == c) {
                int pos = __popcll(m & ((1ull << t) - 1ull));
                s_list[cnt + pos] = base + t;
            }
            cnt += __popcll(m);
        }
        if (t == 0) s_cnt = cnt;
    }
    __syncthreads();
    const int cnt = s_cnt;
    if (cnt == 0) return;

    float* stats_m = ws;
    float* stats_s = ws + Nn * KC;

    const float* qbase = queue + (size_t)c * ((size_t)Dd * Kk)
                       + (size_t)(dq * 64) * Kk + kc * CHUNK + gcol * 4;

    for (int g0 = 0; g0 < cnt; g0 += G) {
        const int gs = min(G, cnt - g0);

        // stage q rows: sq[d][s] = q[list[g0+s]][d]
        for (int i = t; i < Dd * G; i += 256) {
            int d = i >> 3, s = i & 7;
            sq[d][s] = (s < gs) ? q[s_list[g0 + s] * Dd + d] : 0.f;
        }
        __syncthreads();

        // each thread: 4 cols (float4), 64 d's, G samples
        float4 acc[G];
        #pragma unroll
        for (int s = 0; s < G; ++s) acc[s] = make_float4(0.f, 0.f, 0.f, 0.f);

        #pragma unroll 8
        for (int d = 0; d < 64; ++d) {
            float4 v  = *reinterpret_cast<const float4*>(qbase + (size_t)d * Kk);
            float4 qA = *reinterpret_cast<const float4*>(&sq[dq * 64 + d][0]);
            float4 qB = *reinterpret_cast<const float4*>(&sq[dq * 64 + d][4]);
            const float qs[G] = {qA.x, qA.y, qA.z, qA.w, qB.x, qB.y, qB.z, qB.w};
            #pragma unroll
            for (int s = 0; s < G; ++s) {
                acc[s].x = fmaf(qs[s], v.x, acc[s].x);
                acc[s].y = fmaf(qs[s], v.y, acc[s].y);
                acc[s].z = fmaf(qs[s], v.z, acc[s].z);
                acc[s].w = fmaf(qs[s], v.w, acc[s].w);
            }
        }

        // 2-way d-reduce: dq==1 writes, dq==0 adds (conflict-free: consecutive floats)
        if (dq == 1) {
            #pragma unroll
            for (int s = 0; s < G; ++s) {
                part[0][s][gcol] = acc[s].x;
                part[1][s][gcol] = acc[s].y;
                part[2][s][gcol] = acc[s].z;
                part[3][s][gcol] = acc[s].w;
            }
        }
        __syncthreads();

        if (dq == 0) {
            #pragma unroll
            for (int s = 0; s < G; ++s) {
                acc[s].x = (acc[s].x + part[0][s][gcol]) * INV_T;
                acc[s].y = (acc[s].y + part[1][s][gcol]) * INV_T;
                acc[s].z = (acc[s].z + part[2][s][gcol]) * INV_T;
                acc[s].w = (acc[s].w + part[3][s][gcol]) * INV_T;
            }
            // per-sample wave max, all 8 samples in parallel (2 waves active)
            #pragma unroll
            for (int s = 0; s < G; ++s) {
                float mm = fmaxf(fmaxf(acc[s].x, acc[s].y), fmaxf(acc[s].z, acc[s].w));
                #pragma unroll
                for (int off = 32; off >= 1; off >>= 1)
                    mm = fmaxf(mm, __shfl_xor(mm, off, 64));
                if (lane == 0) wmax[wid][s] = mm;
            }
        }
        __syncthreads();

        if (dq == 0) {
            #pragma unroll
            for (int s = 0; s < G; ++s) {
                const float bm = fmaxf(wmax[0][s], wmax[1][s]);
                float e = expf(acc[s].x - bm) + expf(acc[s].y - bm)
                        + expf(acc[s].z - bm) + expf(acc[s].w - bm);
                #pragma unroll
                for (int off = 32; off >= 1; off >>= 1)
                    e += __shfl_xor(e, off, 64);
                if (lane == 0) wsum[wid][s] = e;
            }
        }
        __syncthreads();

        if (t < gs) {
            const int n = s_list[g0 + t];
            stats_m[n * KC + kc] = fmaxf(wmax[0][t], wmax[1][t]);
            stats_s[n * KC + kc] = wsum[0][t] + wsum[1][t];
        }
        __syncthreads();
    }
}

__global__ __launch_bounds__(512) void finish_kernel(
    const float* __restrict__ q, const float* __restrict__ k,
    const float* __restrict__ ws, float* __restrict__ out)
{
    const int t = threadIdx.x;   // one thread per sample
    const float* stats_m = ws;
    const float* stats_s = ws + Nn * KC;

    // l_pos = dot(q[t], k[t]) / T
    float lp = 0.f;
    const float4* qv = reinterpret_cast<const float4*>(q + t * Dd);
    const float4* kv = reinterpret_cast<const float4*>(k + t * Dd);
    #pragma unroll 8
    for (int j = 0; j < Dd / 4; ++j) {
        float4 a = qv[j], b = kv[j];
        lp = fmaf(a.x, b.x, lp); lp = fmaf(a.y, b.y, lp);
        lp = fmaf(a.z, b.z, lp); lp = fmaf(a.w, b.w, lp);
    }
    lp *= INV_T;

    float mm[KC], ss[KC];
    float m = lp;
    #pragma unroll
    for (int j = 0; j < KC; ++j) {
        mm[j] = stats_m[t * KC + j];
        ss[j] = stats_s[t * KC + j];
        m = fmaxf(m, mm[j]);
    }
    float sum = expf(lp - m);
    #pragma unroll
    for (int j = 0; j < KC; ++j) sum += ss[j] * expf(mm[j] - m);
    const float loss = logf(sum) + m - lp;

    __shared__ float red[512];
    red[t] = loss;
    __syncthreads();
    for (int s2 = 256; s2 > 0; s2 >>= 1) {
        if (t < s2) red[t] += red[t + s2];
        __syncthreads();
    }
    if (t == 0) out[0] = red[0] / (float)Nn;
}

extern "C" void kernel_launch(void* const* d_in, const int* in_sizes, int n_in,
                              void* d_out, int out_size, void* d_ws, size_t ws_size,
                              hipStream_t stream) {
    const float* q      = (const float*)d_in[0];
    const float* k      = (const float*)d_in[1];
    const float* queue  = (const float*)d_in[2];
    // d_in[3] = class_weights — unused by the reference computation
    const int* labels   = (const int*)d_in[4];
    float* out          = (float*)d_out;
    float* ws           = (float*)d_ws;

    dim3 grid(KC, Cc);
    chunk_kernel<<<grid, 256, 0, stream>>>(q, queue, labels, ws);
    finish_kernel<<<1, 512, 0, stream>>>(q, k, ws, out);
}

// Round 5
// 59.407 us; speedup vs baseline: 1.1246x; 1.1246x over previous
//
#include <hip/hip_runtime.h>

#define Nn 512
#define Dd 128
#define Kk 2048
#define Cc 100
#define KC 8            // 8 chunks of 256 columns per class
#define G  16           // samples per pass (one pass for any cnt<=16)
constexpr float INV_T = 1.0f / 0.07f;

// ws layout (floats): stats_m[n*KC+kc] in [0, 4096), stats_s in [4096, 8192)

// FMA of one float4 column-group v against 16 broadcast q-values
#define FMA16(q0, q1, q2, q3, v)                                   \
  do {                                                             \
    acc[0].x  = fmaf(q0.x, v.x, acc[0].x);  acc[0].y  = fmaf(q0.x, v.y, acc[0].y);  acc[0].z  = fmaf(q0.x, v.z, acc[0].z);  acc[0].w  = fmaf(q0.x, v.w, acc[0].w);  \
    acc[1].x  = fmaf(q0.y, v.x, acc[1].x);  acc[1].y  = fmaf(q0.y, v.y, acc[1].y);  acc[1].z  = fmaf(q0.y, v.z, acc[1].z);  acc[1].w  = fmaf(q0.y, v.w, acc[1].w);  \
    acc[2].x  = fmaf(q0.z, v.x, acc[2].x);  acc[2].y  = fmaf(q0.z, v.y, acc[2].y);  acc[2].z  = fmaf(q0.z, v.z, acc[2].z);  acc[2].w  = fmaf(q0.z, v.w, acc[2].w);  \
    acc[3].x  = fmaf(q0.w, v.x, acc[3].x);  acc[3].y  = fmaf(q0.w, v.y, acc[3].y);  acc[3].z  = fmaf(q0.w, v.z, acc[3].z);  acc[3].w  = fmaf(q0.w, v.w, acc[3].w);  \
    acc[4].x  = fmaf(q1.x, v.x, acc[4].x);  acc[4].y  = fmaf(q1.x, v.y, acc[4].y);  acc[4].z  = fmaf(q1.x, v.z, acc[4].z);  acc[4].w  = fmaf(q1.x, v.w, acc[4].w);  \
    acc[5].x  = fmaf(q1.y, v.x, acc[5].x);  acc[5].y  = fmaf(q1.y, v.y, acc[5].y);  acc[5].z  = fmaf(q1.y, v.z, acc[5].z);  acc[5].w  = fmaf(q1.y, v.w, acc[5].w);  \
    acc[6].x  = fmaf(q1.z, v.x, acc[6].x);  acc[6].y  = fmaf(q1.z, v.y, acc[6].y);  acc[6].z  = fmaf(q1.z, v.z, acc[6].z);  acc[6].w  = fmaf(q1.z, v.w, acc[6].w);  \
    acc[7].x  = fmaf(q1.w, v.x, acc[7].x);  acc[7].y  = fmaf(q1.w, v.y, acc[7].y);  acc[7].z  = fmaf(q1.w, v.z, acc[7].z);  acc[7].w  = fmaf(q1.w, v.w, acc[7].w);  \
    acc[8].x  = fmaf(q2.x, v.x, acc[8].x);  acc[8].y  = fmaf(q2.x, v.y, acc[8].y);  acc[8].z  = fmaf(q2.x, v.z, acc[8].z);  acc[8].w  = fmaf(q2.x, v.w, acc[8].w);  \
    acc[9].x  = fmaf(q2.y, v.x, acc[9].x);  acc[9].y  = fmaf(q2.y, v.y, acc[9].y);  acc[9].z  = fmaf(q2.y, v.z, acc[9].z);  acc[9].w  = fmaf(q2.y, v.w, acc[9].w);  \
    acc[10].x = fmaf(q2.z, v.x, acc[10].x); acc[10].y = fmaf(q2.z, v.y, acc[10].y); acc[10].z = fmaf(q2.z, v.z, acc[10].z); acc[10].w = fmaf(q2.z, v.w, acc[10].w); \
    acc[11].x = fmaf(q2.w, v.x, acc[11].x); acc[11].y = fmaf(q2.w, v.y, acc[11].y); acc[11].z = fmaf(q2.w, v.z, acc[11].z); acc[11].w = fmaf(q2.w, v.w, acc[11].w); \
    acc[12].x = fmaf(q3.x, v.x, acc[12].x); acc[12].y = fmaf(q3.x, v.y, acc[12].y); acc[12].z = fmaf(q3.x, v.z, acc[12].z); acc[12].w = fmaf(q3.x, v.w, acc[12].w); \
    acc[13].x = fmaf(q3.y, v.x, acc[13].x); acc[13].y = fmaf(q3.y, v.y, acc[13].y); acc[13].z = fmaf(q3.y, v.z, acc[13].z); acc[13].w = fmaf(q3.y, v.w, acc[13].w); \
    acc[14].x = fmaf(q3.z, v.x, acc[14].x); acc[14].y = fmaf(q3.z, v.y, acc[14].y); acc[14].z = fmaf(q3.z, v.z, acc[14].z); acc[14].w = fmaf(q3.z, v.w, acc[14].w); \
    acc[15].x = fmaf(q3.w, v.x, acc[15].x); acc[15].y = fmaf(q3.w, v.y, acc[15].y); acc[15].z = fmaf(q3.w, v.z, acc[15].z); acc[15].w = fmaf(q3.w, v.w, acc[15].w); \
  } while (0)

__global__ __launch_bounds__(64) void chunk_kernel(
    const float* __restrict__ q,
    const float* __restrict__ queue, const int* __restrict__ labels,
    float* __restrict__ ws)
{
    const int c  = blockIdx.x >> 3;      // class
    const int kc = blockIdx.x & 7;       // column chunk
    const int l  = threadIdx.x;          // 0..63, single wave

    __shared__ int   s_list[Nn];
    __shared__ float sq[Dd][G];          // 8 KB, broadcast q rows

    // ballot scan over labels: deterministic ordered sample list for class c
    int cnt = 0;
    for (int base = 0; base < Nn; base += 64) {
        int lab = labels[base + l];
        unsigned long long m = __ballot(lab == c);
        if (lab == c) {
            int pos = __popcll(m & ((1ull << l) - 1ull));
            s_list[cnt + pos] = base + l;
        }
        cnt += __popcll(m);              // wave-uniform
    }
    if (cnt == 0) return;
    __syncthreads();

    float* stats_m = ws;
    float* stats_s = ws + Nn * KC;

    const size_t slab = (size_t)c * Dd * Kk;
    const float4* gp = reinterpret_cast<const float4*>(queue + slab + kc * 256 + l * 4);
    const int RS = Kk / 4;               // row stride in float4

    for (int g0 = 0; g0 < cnt; g0 += G) {
        const int gs = min(G, cnt - g0);

        // stage sq[d][s] transposed: lane (s = l&15, j4 = l>>4) loads float4 chunks
        {
            const int s  = l & 15;
            const int j4 = l >> 4;
            #pragma unroll
            for (int r = 0; r < 8; ++r) {
                const int chunk = r * 4 + j4;        // 0..31
                const int dbase = chunk * 4;
                float4 v = make_float4(0.f, 0.f, 0.f, 0.f);
                if (s < gs)
                    v = *reinterpret_cast<const float4*>(q + s_list[g0 + s] * Dd + dbase);
                sq[dbase + 0][s] = v.x;
                sq[dbase + 1][s] = v.y;
                sq[dbase + 2][s] = v.z;
                sq[dbase + 3][s] = v.w;
            }
        }
        __syncthreads();

        float4 acc[G];
        #pragma unroll
        for (int s = 0; s < G; ++s) acc[s] = make_float4(0.f, 0.f, 0.f, 0.f);

        // 8-deep double-buffered pipeline over 128 d-rows
        float4 A[8], B[8];
        #pragma unroll
        for (int j = 0; j < 8; ++j) A[j] = gp[j * RS];

        for (int d0 = 0; d0 < Dd; d0 += 16) {
            #pragma unroll
            for (int j = 0; j < 8; ++j) B[j] = gp[(d0 + 8 + j) * RS];
            #pragma unroll
            for (int j = 0; j < 8; ++j) {
                const int d = d0 + j;
                const float4 q0 = *reinterpret_cast<const float4*>(&sq[d][0]);
                const float4 q1 = *reinterpret_cast<const float4*>(&sq[d][4]);
                const float4 q2 = *reinterpret_cast<const float4*>(&sq[d][8]);
                const float4 q3 = *reinterpret_cast<const float4*>(&sq[d][12]);
                const float4 v  = A[j];
                FMA16(q0, q1, q2, q3, v);
            }
            #pragma unroll
            for (int j = 0; j < 8; ++j) A[j] = gp[((d0 + 16 + j) & (Dd - 1)) * RS];
            #pragma unroll
            for (int j = 0; j < 8; ++j) {
                const int d = d0 + 8 + j;
                const float4 q0 = *reinterpret_cast<const float4*>(&sq[d][0]);
                const float4 q1 = *reinterpret_cast<const float4*>(&sq[d][4]);
                const float4 q2 = *reinterpret_cast<const float4*>(&sq[d][8]);
                const float4 q3 = *reinterpret_cast<const float4*>(&sq[d][12]);
                const float4 v  = B[j];
                FMA16(q0, q1, q2, q3, v);
            }
        }

        // per-sample softmax stats over this wave's 256 logits
        float myM = 0.f, myS = 0.f;
        #pragma unroll
        for (int s = 0; s < G; ++s) {
            float lx = acc[s].x * INV_T, ly = acc[s].y * INV_T;
            float lz = acc[s].z * INV_T, lw = acc[s].w * INV_T;
            float m = fmaxf(fmaxf(lx, ly), fmaxf(lz, lw));
            #pragma unroll
            for (int off = 32; off >= 1; off >>= 1)
                m = fmaxf(m, __shfl_xor(m, off, 64));
            float e = expf(lx - m) + expf(ly - m) + expf(lz - m) + expf(lw - m);
            #pragma unroll
            for (int off = 32; off >= 1; off >>= 1)
                e += __shfl_xor(e, off, 64);
            if (l == s) { myM = m; myS = e; }
        }
        if (l < gs) {
            const int n = s_list[g0 + l];
            stats_m[n * KC + kc] = myM;
            stats_s[n * KC + kc] = myS;
        }
        __syncthreads();
    }
}

__global__ __launch_bounds__(512) void finish_kernel(
    const float* __restrict__ q, const float* __restrict__ k,
    const float* __restrict__ ws, float* __restrict__ out)
{
    const int t = threadIdx.x;   // one thread per sample
    const float* stats_m = ws;
    const float* stats_s = ws + Nn * KC;

    // l_pos = dot(q[t], k[t]) / T
    float lp = 0.f;
    const float4* qv = reinterpret_cast<const float4*>(q + t * Dd);
    const float4* kv = reinterpret_cast<const float4*>(k + t * Dd);
    #pragma unroll 8
    for (int j = 0; j < Dd / 4; ++j) {
        float4 a = qv[j], b = kv[j];
        lp = fmaf(a.x, b.x, lp); lp = fmaf(a.y, b.y, lp);
        lp = fmaf(a.z, b.z, lp); lp = fmaf(a.w, b.w, lp);
    }
    lp *= INV_T;

    float m = lp;
    float mm[KC], ss[KC];
    #pragma unroll
    for (int j = 0; j < KC; ++j) {
        mm[j] = stats_m[t * KC + j];
        ss[j] = stats_s[t * KC + j];
        m = fmaxf(m, mm[j]);
    }
    float sum = expf(lp - m);
    #pragma unroll
    for (int j = 0; j < KC; ++j) sum += ss[j] * expf(mm[j] - m);
    const float loss = logf(sum) + m - lp;

    __shared__ float red[512];
    red[t] = loss;
    __syncthreads();
    for (int s2 = 256; s2 > 0; s2 >>= 1) {
        if (t < s2) red[t] += red[t + s2];
        __syncthreads();
    }
    if (t == 0) out[0] = red[0] / (float)Nn;
}

extern "C" void kernel_launch(void* const* d_in, const int* in_sizes, int n_in,
                              void* d_out, int out_size, void* d_ws, size_t ws_size,
                              hipStream_t stream) {
    const float* q      = (const float*)d_in[0];
    const float* k      = (const float*)d_in[1];
    const float* queue  = (const float*)d_in[2];
    // d_in[3] = class_weights — unused by the reference computation
    const int* labels   = (const int*)d_in[4];
    float* out          = (float*)d_out;
    float* ws           = (float*)d_ws;

    chunk_kernel<<<Cc * KC, 64, 0, stream>>>(q, queue, labels, ws);
    finish_kernel<<<1, 512, 0, stream>>>(q, k, ws, out);
}

// Round 6
// 49.603 us; speedup vs baseline: 1.3469x; 1.1976x over previous
//
#include <hip/hip_runtime.h>

#define Nn 512
#define Dd 128
#define Kk 2048
#define Cc 100
#define KC 16           // 16 chunks of 128 columns per class
#define G  8            // samples per pass
constexpr float INV_T = 1.0f / 0.07f;

// ws layout (floats): stats_m[n*KC+kc] in [0, 8192), stats_s in [8192, 16384)

__global__ __launch_bounds__(256) void chunk_kernel(
    const float* __restrict__ q,
    const float* __restrict__ queue, const int* __restrict__ labels,
    float* __restrict__ ws)
{
    const int c    = blockIdx.x >> 4;    // class
    const int kc   = blockIdx.x & 15;    // 128-col chunk
    const int t    = threadIdx.x;
    const int col4 = t & 31;             // float4 column group (4 cols)
    const int dg   = t >> 5;             // d-group 0..7, 16 rows each

    __shared__ int   s_list[Nn];
    __shared__ int   s_cnt;
    __shared__ float sq[G][Dd];          // sample-major staged q rows, 4 KB
    __shared__ float pbuf[8][G][Dd];     // [dg][sample][col] partials, 32 KB

    // wave-0 ballot scan: deterministic ordered list of samples with label c
    if (t < 64) {
        int cnt = 0;
        for (int base = 0; base < Nn; base += 64) {
            int lab = labels[base + t];
            unsigned long long m = __ballot(lab == c);
            if (lab == c) {
                int pos = __popcll(m & ((1ull << t) - 1ull));
                s_list[cnt + pos] = base + t;
            }
            cnt += __popcll(m);
        }
        if (t == 0) s_cnt = cnt;
    }
    __syncthreads();
    const int cnt = s_cnt;
    if (cnt == 0) return;                 // uniform across block

    float* stats_m = ws;
    float* stats_s = ws + Nn * KC;

    const float* gbase = queue + (size_t)c * Dd * Kk + kc * 128 + col4 * 4;

    for (int g0 = 0; g0 < cnt; g0 += G) {
        const int gs = min(G, cnt - g0);

        // stage sq[s][d]: thread (s = t>>5, dch = t&31) loads one float4 (conflict-free)
        {
            const int s   = t >> 5;
            const int dch = t & 31;
            float4 v = make_float4(0.f, 0.f, 0.f, 0.f);
            if (s < gs)
                v = *reinterpret_cast<const float4*>(q + s_list[g0 + s] * Dd + dch * 4);
            *reinterpret_cast<float4*>(&sq[s][dch * 4]) = v;
        }
        __syncthreads();

        // 16 independent float4 loads issued up-front (16-deep MLP)
        float4 V[16];
        #pragma unroll
        for (int j = 0; j < 16; ++j)
            V[j] = *reinterpret_cast<const float4*>(gbase + (size_t)(dg * 16 + j) * Kk);

        float4 acc[G];
        #pragma unroll
        for (int s = 0; s < G; ++s) acc[s] = make_float4(0.f, 0.f, 0.f, 0.f);

        #pragma unroll
        for (int j = 0; j < 16; ++j) {
            const int d = dg * 16 + j;
            const float4 v = V[j];
            #pragma unroll
            for (int s = 0; s < G; ++s) {
                const float qd = sq[s][d];
                acc[s].x = fmaf(qd, v.x, acc[s].x);
                acc[s].y = fmaf(qd, v.y, acc[s].y);
                acc[s].z = fmaf(qd, v.z, acc[s].z);
                acc[s].w = fmaf(qd, v.w, acc[s].w);
            }
        }

        // write d-group partials (float4, conflict-free)
        #pragma unroll
        for (int s = 0; s < G; ++s)
            *reinterpret_cast<float4*>(&pbuf[dg][s][col4 * 4]) = acc[s];
        __syncthreads();

        // reduce 8 d-groups: 32-lane group per sample (s2 = t>>5)
        {
            const int s2 = t >> 5;
            float4 tot = make_float4(0.f, 0.f, 0.f, 0.f);
            #pragma unroll
            for (int g = 0; g < 8; ++g) {
                float4 p = *reinterpret_cast<const float4*>(&pbuf[g][s2][col4 * 4]);
                tot.x += p.x; tot.y += p.y; tot.z += p.z; tot.w += p.w;
            }
            const float lx = tot.x * INV_T, ly = tot.y * INV_T;
            const float lz = tot.z * INV_T, lw = tot.w * INV_T;

            float m4 = fmaxf(fmaxf(lx, ly), fmaxf(lz, lw));
            #pragma unroll
            for (int off = 16; off >= 1; off >>= 1)
                m4 = fmaxf(m4, __shfl_xor(m4, off, 32));
            float e = expf(lx - m4) + expf(ly - m4) + expf(lz - m4) + expf(lw - m4);
            #pragma unroll
            for (int off = 16; off >= 1; off >>= 1)
                e += __shfl_xor(e, off, 32);

            if ((t & 31) == 0 && s2 < gs) {
                const int n = s_list[g0 + s2];
                stats_m[n * KC + kc] = m4;
                stats_s[n * KC + kc] = e;
            }
        }
        __syncthreads();
    }
}

__global__ __launch_bounds__(512) void finish_kernel(
    const float* __restrict__ q, const float* __restrict__ k,
    const float* __restrict__ ws, float* __restrict__ out)
{
    const int t = threadIdx.x;   // one thread per sample
    const float* stats_m = ws;
    const float* stats_s = ws + Nn * KC;

    // l_pos = dot(q[t], k[t]) / T
    float lp = 0.f;
    const float4* qv = reinterpret_cast<const float4*>(q + t * Dd);
    const float4* kv = reinterpret_cast<const float4*>(k + t * Dd);
    #pragma unroll 8
    for (int j = 0; j < Dd / 4; ++j) {
        float4 a = qv[j], b = kv[j];
        lp = fmaf(a.x, b.x, lp); lp = fmaf(a.y, b.y, lp);
        lp = fmaf(a.z, b.z, lp); lp = fmaf(a.w, b.w, lp);
    }
    lp *= INV_T;

    float m = lp;
    float mm[KC], ss[KC];
    #pragma unroll
    for (int j = 0; j < KC; ++j) {
        mm[j] = stats_m[t * KC + j];
        ss[j] = stats_s[t * KC + j];
        m = fmaxf(m, mm[j]);
    }
    float sum = expf(lp - m);
    #pragma unroll
    for (int j = 0; j < KC; ++j) sum += ss[j] * expf(mm[j] - m);
    const float loss = logf(sum) + m - lp;

    __shared__ float red[512];
    red[t] = loss;
    __syncthreads();
    for (int s2 = 256; s2 > 0; s2 >>= 1) {
        if (t < s2) red[t] += red[t + s2];
        __syncthreads();
    }
    if (t == 0) out[0] = red[0] / (float)Nn;
}

extern "C" void kernel_launch(void* const* d_in, const int* in_sizes, int n_in,
                              void* d_out, int out_size, void* d_ws, size_t ws_size,
                              hipStream_t stream) {
    const float* q      = (const float*)d_in[0];
    const float* k      = (const float*)d_in[1];
    const float* queue  = (const float*)d_in[2];
    // d_in[3] = class_weights — unused by the reference computation
    const int* labels   = (const int*)d_in[4];
    float* out          = (float*)d_out;
    float* ws           = (float*)d_ws;

    chunk_kernel<<<Cc * KC, 256, 0, stream>>>(q, queue, labels, ws);
    finish_kernel<<<1, 512, 0, stream>>>(q, k, ws, out);
}